// Round 9
// baseline (550.502 us; speedup 1.0000x reference)
//
#include <hip/hip_runtime.h>

#define Vn    12288
#define En    98304
#define Mrows 98304   // V*B

typedef unsigned short u16;
typedef u16   u16x8  __attribute__((ext_vector_type(8)));
typedef __bf16 bf16x8 __attribute__((ext_vector_type(8)));
typedef float f32x4  __attribute__((ext_vector_type(4)));

struct __align__(8) Edge { int s; float w; };

__device__ __forceinline__ float bf2f(u16 u) {
    union { float f; unsigned int i; } c; c.i = ((unsigned int)u) << 16; return c.f;
}
__device__ __forceinline__ u16 f2bf(float f) {
    union { float f; unsigned int i; } c; c.f = f;
    unsigned int r = c.i + 0x7fffu + ((c.i >> 16) & 1u);  // RNE
    return (u16)(r >> 16);
}
__device__ __forceinline__ void load_lds16(const void* g, void* l) {
    __builtin_amdgcn_global_load_lds(
        (const __attribute__((address_space(1))) void*)g,
        (__attribute__((address_space(3))) void*)l, 16, 0, 0);
}

// ---------- x [B][V][256] f32  ->  xb [V][B*256] bf16 (== flat [m=v*8+b][256]) ----------
// x is read exactly once: non-temporal loads keep L3 free for xb/CSR ahead of lmul.
__global__ void cvt_k(const float* __restrict__ x, u16* __restrict__ xb) {
    int v = blockIdx.x;
    int t = threadIdx.x;
    int b = t >> 5, i = (t & 31) * 8;
    const float* p = x + ((size_t)b * Vn + v) * 256 + i;
    f32x4 a0 = __builtin_nontemporal_load((const f32x4*)p);
    f32x4 a1 = __builtin_nontemporal_load((const f32x4*)(p + 4));
    u16x8 r;
    #pragma unroll
    for (int j = 0; j < 4; ++j) { r[j] = f2bf(a0[j]); r[4 + j] = f2bf(a1[j]); }
    *(u16x8*)(xb + (size_t)v * 2048 + b * 256 + i) = r;
}

// ---------- Wt[o][kk] = bf16(W[kk][o]) ----------
// LDS-staged transpose: coalesced 128B reads, contiguous 16B/lane writes.
// LDS row padded +2 u16 (stride 2052B -> 32-lane o-column hits 32 distinct banks).
__global__ void wtrans_k(const float* __restrict__ w, u16* __restrict__ wt) {
    __shared__ u16 tile[32][1026];
    int o0 = blockIdx.x * 32;                 // grid 8
    int t  = threadIdx.x;                     // 256
    int lo = t & 31;                          // o lane
    int kr = t >> 5;                          // kk subrow 0..7
    for (int kk0 = 0; kk0 < 1024; kk0 += 8) {
        int kk = kk0 + kr;
        tile[lo][kk] = f2bf(w[(size_t)kk * 256 + o0 + lo]);
    }
    __syncthreads();
    // 32 rows x 128 u16x8 chunks = 4096 chunks; 16 per thread
    for (int i = 0; i < 16; ++i) {
        int ch = i * 256 + t;
        int r = ch >> 7, c = ch & 127;
        u16x8 vv = *(const u16x8*)(&tile[r][c * 8]);
        *(u16x8*)(wt + (size_t)(o0 + r) * 1024 + c * 8) = vv;
    }
}

// ---------- CSR build ----------
__global__ void count_k(const int* __restrict__ dst, int* __restrict__ counts) {
    int e = blockIdx.x * 256 + threadIdx.x;   // E = 384*256
    atomicAdd(&counts[dst[e]], 1);
}

__global__ void scan_k(const int* __restrict__ counts, int* __restrict__ row_start,
                       int* __restrict__ cursor) {
    __shared__ int par[1024];
    int t = threadIdx.x;
    int base = t * 12;                        // V = 1024*12
    int s = 0;
    #pragma unroll
    for (int i = 0; i < 12; ++i) s += counts[base + i];
    par[t] = s;
    __syncthreads();
    for (int off = 1; off < 1024; off <<= 1) {
        int v_ = (t >= off) ? par[t - off] : 0;
        __syncthreads();
        par[t] += v_;
        __syncthreads();
    }
    int run = (t == 0) ? 0 : par[t - 1];
    for (int i = 0; i < 12; ++i) {
        row_start[base + i] = run;
        cursor[base + i]    = run;
        run += counts[base + i];
    }
    if (t == 1023) row_start[Vn] = En;        // sentinel
}

__global__ void fill_k(const int* __restrict__ src, const int* __restrict__ dst,
                       const float* __restrict__ ew, int* __restrict__ cursor,
                       Edge* __restrict__ csr) {
    int e = blockIdx.x * 256 + threadIdx.x;
    int d = dst[e];
    int p = atomicAdd(&cursor[d], 1);
    Edge ed; ed.s = src[e]; ed.w = ew[e];
    csr[p] = ed;
}

// ---------- sparse L apply + Chebyshev combine, XCD-sliced by batch ----------
// r7 form EXACT (best measured; separate launches for cross-XCD coherence --
// the r8 cooperative merge mis-read stale L2, launch boundaries do the flush).
// 8 slices x 512B; slice = blockIdx & 7; per-XCD gather working set 6.3 MB.
// PREV: 0 -> out = L y ; 1 -> out = 2 L y - prev   (bf16 node-major [V][2048])
template<int PREV>
__global__ __launch_bounds__(256)
void lmul_k(const u16* __restrict__ yb, const u16* __restrict__ prevb,
            u16* __restrict__ outb, const int* __restrict__ row_start,
            const Edge* __restrict__ csr)
{
    int slice = blockIdx.x & 7;
    int v     = (blockIdx.x >> 3) * 8 + (threadIdx.x >> 5);
    int t     = threadIdx.x & 31;
    int s0    = row_start[v];
    int cnt   = row_start[v + 1] - s0;
    size_t soff = (size_t)slice * 256 + (size_t)t * 8;
    float acc[8] = {0.f,0.f,0.f,0.f,0.f,0.f,0.f,0.f};
    for (int j0 = 0; j0 < cnt; j0 += 8) {
        int ss[8]; float ww[8];
        #pragma unroll
        for (int u = 0; u < 8; ++u) {
            int j = j0 + u;
            bool ok = j < cnt;
            Edge e = csr[s0 + (ok ? j : 0)];
            ss[u] = e.s; ww[u] = ok ? e.w : 0.f;
        }
        u16x8 g[8];
        #pragma unroll
        for (int u = 0; u < 8; ++u)
            g[u] = *(const u16x8*)(yb + (size_t)ss[u] * 2048 + soff);
        #pragma unroll
        for (int u = 0; u < 8; ++u)
            #pragma unroll
            for (int j8 = 0; j8 < 8; ++j8) acc[j8] += ww[u] * bf2f(g[u][j8]);
    }
    u16x8 r;
    if (PREV) {
        u16x8 pu = *(const u16x8*)(prevb + (size_t)v * 2048 + soff);
        #pragma unroll
        for (int j8 = 0; j8 < 8; ++j8) r[j8] = f2bf(2.0f * acc[j8] - bf2f(pu[j8]));
    } else {
        #pragma unroll
        for (int j8 = 0; j8 < 8; ++j8) r[j8] = f2bf(acc[j8]);
    }
    *(u16x8*)(outb + (size_t)v * 2048 + soff) = r;
}

// ---------- GEMM + fused BN/ReLU (persistent) ----------
// Per-tile structure = r7 EXACT: BM=128, BN=256, BK=64; 8 waves 2(m)x4(n), 4x4
// of 16x16x32 MFMA; XOR chunk swizzle; triple-buffered LDS, ONE raw s_barrier
// per K-tile, counted vmcnt(6), distance-2 prefetch, setprio; bf16-C LDS
// epilogue with full-row stores (cb aliases x1; per-tile exclusive rows).
// NEW: persistent grid of 256 blocks (= CU count; 147KB LDS forces 1 block/CU
// so all 256 are co-resident -> spin is deadlock-free). Each block does 3
// m-tiles, then counter handshake (device-scope atomics only -- coherent across
// XCDs), then computes scale/shift and normalizes ITS OWN rows (own-L2 data,
// plain loads safe), writing final f32 output NT. Removes the bn_relu dispatch.
__device__ __forceinline__ void stage_tile(const u16* __restrict__ Ak, int k0,
                                           const u16* __restrict__ wt, int kt,
                                           int m0, int tid, int wave,
                                           char* bufA, char* bufB)
{
    // A tile: 128 rows x 64k = 16KB = 1024 chunks; 2 per thread
    #pragma unroll
    for (int r = 0; r < 2; ++r) {
        int g  = r * 512 + tid;
        int ml = g >> 3;
        int c  = (g & 7) ^ (ml & 7);
        load_lds16(Ak + ((size_t)(m0 + ml)) * 256 + k0 + c * 8,
                   bufA + r * 8192 + wave * 1024);
    }
    // B tile: 256 o-rows x 64k = 32KB = 2048 chunks; 4 per thread
    #pragma unroll
    for (int r = 0; r < 4; ++r) {
        int g = r * 512 + tid;
        int o = g >> 3;
        int c = (g & 7) ^ (o & 7);
        load_lds16(wt + (size_t)o * 1024 + kt * 64 + c * 8,
                   bufB + r * 8192 + wave * 1024);
    }
}

__global__ __launch_bounds__(512)
void gemm_k(const u16* __restrict__ x0, const u16* __restrict__ x1,
            const u16* __restrict__ x2, const u16* __restrict__ x3,
            const u16* __restrict__ wt, const float* __restrict__ bias,
            u16* cbp, float* __restrict__ sums, float* __restrict__ sumsq,
            int* counter, const float* __restrict__ gamma,
            const float* __restrict__ beta, float* __restrict__ outp)
{
    alignas(16) __shared__ char lds[147456];  // 3 bufs x (A 16KB @ +0, B 32KB @ +16384)
    int tid  = threadIdx.x;
    int wave = tid >> 6;                      // 0..7
    int lane = tid & 63;
    int wm   = wave & 1;                      // m-half (0/1)
    int wn   = wave >> 1;                     // n-quarter (0..3)
    int crow = lane & 15, quad = lane >> 4;

    for (int it = 0; it < 3; ++it) {
        int m0 = (blockIdx.x * 3 + it) * 128;

        f32x4 acc[4][4];
        #pragma unroll
        for (int a = 0; a < 4; ++a)
            #pragma unroll
            for (int b = 0; b < 4; ++b) acc[a][b] = (f32x4){0.f,0.f,0.f,0.f};

        // prologue: stage tiles 0 and 1 (kt=0: ks=0,k0=0; kt=1: ks=0,k0=64)
        stage_tile(x0, 0,  wt, 0, m0, tid, wave, (char*)lds,         (char*)lds + 16384);
        stage_tile(x0, 64, wt, 1, m0, tid, wave, (char*)lds + 49152, (char*)lds + 49152 + 16384);

        int cb = 0;   // compute buffer (tile t lives in buf t%3)
        int pb = 2;   // prefetch buffer (tile t+2)
        for (int t = 0; t < 16; ++t) {
            // tile t's 6 loads done; tile t+1's 6 remain in flight (last: drain).
            // (epilogue stores/atomics from the previous m-tile also count in
            // vmcnt -> waits are conservative, still correct)
            if (t < 15) asm volatile("s_waitcnt vmcnt(6) lgkmcnt(0)" ::: "memory");
            else        asm volatile("s_waitcnt vmcnt(0) lgkmcnt(0)" ::: "memory");
            __builtin_amdgcn_s_barrier();
            __builtin_amdgcn_sched_barrier(0);
            if (t < 14) {
                int kt = t + 2;
                int ks = kt >> 2;
                int k0 = (kt & 3) * 64;
                const u16* Ak = (ks == 0) ? x0 : (ks == 1) ? x1 : (ks == 2) ? x2 : x3;
                stage_tile(Ak, k0, wt, kt, m0, tid, wave,
                           (char*)lds + pb * 49152, (char*)lds + pb * 49152 + 16384);
            }
            const char* Ab = (const char*)lds + cb * 49152;
            const char* Bb = Ab + 16384;
            #pragma unroll
            for (int kstep = 0; kstep < 2; ++kstep) {
                int cidx = kstep * 4 + (lane >> 4);
                int row  = lane & 15;
                bf16x8 af[4], bfr[4];
                #pragma unroll
                for (int mt = 0; mt < 4; ++mt) {
                    int m16 = wm * 64 + mt * 16 + row;
                    af[mt] = *(const bf16x8*)(Ab + (size_t)(m16 * 8 + (cidx ^ (m16 & 7))) * 16);
                }
                #pragma unroll
                for (int nt = 0; nt < 4; ++nt) {
                    int ol = wn * 64 + nt * 16 + row;
                    bfr[nt] = *(const bf16x8*)(Bb + (size_t)(ol * 8 + (cidx ^ (ol & 7))) * 16);
                }
                __builtin_amdgcn_s_setprio(1);
                #pragma unroll
                for (int mt = 0; mt < 4; ++mt)
                    #pragma unroll
                    for (int nt = 0; nt < 4; ++nt)
                        acc[mt][nt] = __builtin_amdgcn_mfma_f32_16x16x32_bf16(
                            af[mt], bfr[nt], acc[mt][nt], 0, 0, 0);
                __builtin_amdgcn_s_setprio(0);
            }
            cb = (cb == 2) ? 0 : cb + 1;
            pb = (pb == 2) ? 0 : pb + 1;
        }

        // ---- per-tile epilogue ----
        // Phase 1: quantize to bf16, write LDS tile [128][256] (64KB @ lds+0),
        // 16B-chunk XOR swizzle; BN stats from the QUANTIZED values.
        __syncthreads();   // all waves done reading tile-15 fragments
        #pragma unroll
        for (int nt = 0; nt < 4; ++nt) {
            int o = wn * 64 + nt * 16 + crow;
            int c_o = o >> 3, o_in = (o & 7) * 2;
            float bv = bias[o];
            float ps = 0.f, pq = 0.f;
            #pragma unroll
            for (int mt = 0; mt < 4; ++mt) {
                #pragma unroll
                for (int r = 0; r < 4; ++r) {
                    int ml = wm * 64 + mt * 16 + quad * 4 + r;
                    u16 q = f2bf(acc[mt][nt][r] + bv);
                    float vq = bf2f(q);
                    *(u16*)(lds + (size_t)ml * 512 + (size_t)(c_o ^ (ml & 7)) * 16 + o_in) = q;
                    ps += vq; pq += vq * vq;
                }
            }
            ps += __shfl_down(ps, 32, 64);  pq += __shfl_down(pq, 32, 64);
            ps += __shfl_down(ps, 16, 64);  pq += __shfl_down(pq, 16, 64);
            if (quad == 0) { atomicAdd(&sums[o], ps); atomicAdd(&sumsq[o], pq); }
        }
        __syncthreads();
        // Phase 2: stream out contiguous full rows. 4096 chunks of 16B; 8/thread.
        #pragma unroll
        for (int rr = 0; rr < 8; ++rr) {
            int ch = rr * 512 + tid;
            int ml = ch >> 5, c = ch & 31;
            u16x8 vv = *(const u16x8*)(lds + (size_t)ml * 512 + (size_t)(c ^ (ml & 7)) * 16);
            *(u16x8*)(cbp + (size_t)(m0 + ml) * 256 + c * 8) = vv;
        }
        __syncthreads();   // LDS free before next tile's prologue staging
    }

    // ---- handshake: all 256 blocks co-resident; device-scope atomics only ----
    __threadfence();                           // stats adds globally visible
    __syncthreads();
    if (tid == 0) {
        __hip_atomic_fetch_add(counter, 1, __ATOMIC_ACQ_REL, __HIP_MEMORY_SCOPE_AGENT);
        while (__hip_atomic_load(counter, __ATOMIC_ACQUIRE, __HIP_MEMORY_SCOPE_AGENT) < 256)
            __builtin_amdgcn_s_sleep(8);
    }
    __syncthreads();

    // scale/shift (atomic loads of sums/sumsq -- coherent across XCDs)
    float* ssc = (float*)lds;
    float* ssh = (float*)(lds + 1024);
    if (tid < 256) {
        const float invM = 1.0f / (float)Mrows;
        float s = __hip_atomic_load(&sums[tid],  __ATOMIC_RELAXED, __HIP_MEMORY_SCOPE_AGENT);
        float q = __hip_atomic_load(&sumsq[tid], __ATOMIC_RELAXED, __HIP_MEMORY_SCOPE_AGENT);
        float mean = s * invM;
        float var  = q * invM - mean * mean;
        float sc   = gamma[tid] * rsqrtf(var + 1e-5f);
        ssc[tid] = sc;
        ssh[tid] = beta[tid] - mean * sc;
    }
    __syncthreads();

    // normalize OWN rows (cb lines written by this block -> own L2, plain loads
    // safe). cb [m][256] bf16 -> out [b][v][256] f32 (m = v*8+b), BN+ReLU, NT.
    for (int it = 0; it < 3; ++it) {
        int m0 = (blockIdx.x * 3 + it) * 128;
        #pragma unroll
        for (int i = 0; i < 8; ++i) {          // 4096 u16x8 chunks / 512 thr
            int ch = i * 512 + tid;
            int ml = ch >> 5, c = ch & 31;
            int m  = m0 + ml;
            int o0 = c * 8;
            u16x8 v = *(const u16x8*)(cbp + (size_t)m * 256 + o0);
            float* dst = outp + ((size_t)((m & 7) * Vn + (m >> 3))) * 256 + o0;
            f32x4 a, cc;
            #pragma unroll
            for (int j = 0; j < 4; ++j) {
                a[j]  = fmaxf(bf2f(v[j])     * ssc[o0 + j]     + ssh[o0 + j],     0.f);
                cc[j] = fmaxf(bf2f(v[4 + j]) * ssc[o0 + 4 + j] + ssh[o0 + 4 + j], 0.f);
            }
            __builtin_nontemporal_store(a,  (f32x4*)dst);
            __builtin_nontemporal_store(cc, (f32x4*)(dst + 4));
        }
    }
}

extern "C" void kernel_launch(void* const* d_in, const int* in_sizes, int n_in,
                              void* d_out, int out_size, void* d_ws, size_t ws_size,
                              hipStream_t stream) {
    const float* x     = (const float*)d_in[0];
    const float* ew    = (const float*)d_in[1];
    const float* w     = (const float*)d_in[2];
    const float* bias  = (const float*)d_in[3];
    const float* gamma = (const float*)d_in[4];
    const float* beta  = (const float*)d_in[5];
    const int*   esrc  = (const int*)d_in[6];
    const int*   edst  = (const int*)d_in[7];
    float* outp = (float*)d_out;
    char*  ws   = (char*)d_ws;

    u16*   xb        = (u16*)  (ws + 0);           // 50331648 B each, bf16 [V][2048]
    u16*   x1        = (u16*)  (ws + 50331648);
    u16*   x2        = (u16*)  (ws + 100663296);
    u16*   x3        = (u16*)  (ws + 150994944);
    u16*   wt        = (u16*)  (ws + 201326592);   // 524288 B
    Edge*  csr       = (Edge*) (ws + 201850880);   // 786432 B
    int*   counts    = (int*)  (ws + 202637312);   // 49152 B
    int*   row_start = (int*)  (ws + 202686464);   // 49412 B (V+1)
    int*   cursor    = (int*)  (ws + 202736128);   // 49152 B
    float* sums      = (float*)(ws + 202785280);   // 1024 B
    float* sumsq     = (float*)(ws + 202786304);   // 1024 B
    int*   counter   = (int*)  (ws + 202787328);   // 4 B

    hipMemsetAsync(counts, 0, 49152, stream);
    hipMemsetAsync(sums, 0, 2052, stream);         // sums + sumsq + counter

    cvt_k<<<Vn, 256, 0, stream>>>(x, xb);
    wtrans_k<<<8, 256, 0, stream>>>(w, wt);
    count_k<<<384, 256, 0, stream>>>(edst, counts);
    scan_k<<<1, 1024, 0, stream>>>(counts, row_start, cursor);
    fill_k<<<384, 256, 0, stream>>>(esrc, edst, ew, cursor, csr);

    // T1 = L x ; T2 = 2 L T1 - x ; T3 = 2 L T2 - T1   (all bf16 node-major)
    lmul_k<0><<<Vn, 256, 0, stream>>>(xb, nullptr, x1, row_start, csr);
    lmul_k<1><<<Vn, 256, 0, stream>>>(x1, xb,      x2, row_start, csr);
    lmul_k<1><<<Vn, 256, 0, stream>>>(x2, x1,      x3, row_start, csr);

    // Persistent GEMM (256 blocks, 3 m-tiles each) + fused finalize+BN+ReLU.
    // C (bf16, [m][256]) aliases x1 -- per-tile exclusive rows.
    gemm_k<<<256, 512, 0, stream>>>(xb, x1, x2, x3, wt, bias,
                                    (u16*)x1, sums, sumsq, counter,
                                    gamma, beta, outp);
}

// Round 10
// 457.200 us; speedup vs baseline: 1.2041x; 1.2041x over previous
//
#include <hip/hip_runtime.h>

#define Vn    12288
#define En    98304
#define Mrows 98304   // V*B

typedef unsigned short u16;
typedef u16   u16x8  __attribute__((ext_vector_type(8)));
typedef __bf16 bf16x8 __attribute__((ext_vector_type(8)));
typedef float f32x4  __attribute__((ext_vector_type(4)));

struct __align__(8) Edge { int s; float w; };

__device__ __forceinline__ float bf2f(u16 u) {
    union { float f; unsigned int i; } c; c.i = ((unsigned int)u) << 16; return c.f;
}
__device__ __forceinline__ u16 f2bf(float f) {
    union { float f; unsigned int i; } c; c.f = f;
    unsigned int r = c.i + 0x7fffu + ((c.i >> 16) & 1u);  // RNE
    return (u16)(r >> 16);
}
__device__ __forceinline__ void load_lds16(const void* g, void* l) {
    __builtin_amdgcn_global_load_lds(
        (const __attribute__((address_space(1))) void*)g,
        (__attribute__((address_space(3))) void*)l, 16, 0, 0);
}

// ---------- merged prologue: cvt | wtrans | count | zero-stats ----------
// The three sub-kernels are mutually independent (cvt: x->xb; wtrans: w->wt;
// count: edst->counts) so one dispatch partitioned by blockIdx range is safe.
// Saves 2 dispatch gaps + 1 memset dispatch (stats zeroed by the last block;
// gemm reads them 5 launch boundaries later).
// wtrans runs in 4 kk-chunks so static LDS is 16.5KB (kernel-wide!) and the
// 12288 cvt blocks keep high occupancy.
__global__ __launch_bounds__(256)
void prep_k(const float* __restrict__ x, u16* __restrict__ xb,
            const float* __restrict__ w, u16* __restrict__ wt,
            const int* __restrict__ edst, int* __restrict__ counts,
            float* __restrict__ sums)
{
    __shared__ u16 tile[32][258];             // wtrans staging (stride 516B ==
    int bid = blockIdx.x;                     // 129 dw == 1 mod 32: conflict-free)
    int t   = threadIdx.x;
    if (bid < Vn) {
        // ---- cvt: x [B][V][256] f32 -> xb [V][B*256] bf16 (m = v*8+b) ----
        // x read exactly once -> NT loads keep L3 free for xb ahead of lmul.
        int v = bid;
        int b = t >> 5, i = (t & 31) * 8;
        const float* p = x + ((size_t)b * Vn + v) * 256 + i;
        f32x4 a0 = __builtin_nontemporal_load((const f32x4*)p);
        f32x4 a1 = __builtin_nontemporal_load((const f32x4*)(p + 4));
        u16x8 r;
        #pragma unroll
        for (int j = 0; j < 4; ++j) { r[j] = f2bf(a0[j]); r[4 + j] = f2bf(a1[j]); }
        *(u16x8*)(xb + (size_t)v * 2048 + b * 256 + i) = r;
    } else if (bid < Vn + 8) {
        // ---- wtrans: Wt[o][kk] = bf16(W[kk][o]), LDS-staged transpose ----
        int o0 = (bid - Vn) * 32;
        int lo = t & 31;                      // o lane
        int kr = t >> 5;                      // kk subrow 0..7
        for (int kc = 0; kc < 4; ++kc) {
            #pragma unroll
            for (int kk0 = 0; kk0 < 256; kk0 += 8) {
                int kk = kc * 256 + kk0 + kr;
                tile[lo][kk0 + kr] = f2bf(w[(size_t)kk * 256 + o0 + lo]);
            }
            __syncthreads();
            // 32 rows x 32 u16x8 chunks = 1024 chunks; 4 per thread
            #pragma unroll
            for (int i2 = 0; i2 < 4; ++i2) {
                int ch = i2 * 256 + t;
                int r2 = ch >> 5, c2 = ch & 31;
                u16x8 vv = *(const u16x8*)(&tile[r2][c2 * 8]);
                *(u16x8*)(wt + (size_t)(o0 + r2) * 1024 + kc * 256 + c2 * 8) = vv;
            }
            __syncthreads();
        }
    } else if (bid < Vn + 8 + 384) {
        // ---- count: histogram of edge destinations ----
        int e = (bid - Vn - 8) * 256 + t;     // E = 384*256
        atomicAdd(&counts[edst[e]], 1);
    } else {
        // ---- zero sums+sumsq (adjacent, 512 floats) ----
        sums[t] = 0.f; sums[256 + t] = 0.f;
    }
}

// ---------- CSR build ----------
__global__ void scan_k(const int* __restrict__ counts, int* __restrict__ row_start,
                       int* __restrict__ cursor) {
    __shared__ int par[1024];
    int t = threadIdx.x;
    int base = t * 12;                        // V = 1024*12
    int s = 0;
    #pragma unroll
    for (int i = 0; i < 12; ++i) s += counts[base + i];
    par[t] = s;
    __syncthreads();
    for (int off = 1; off < 1024; off <<= 1) {
        int v_ = (t >= off) ? par[t - off] : 0;
        __syncthreads();
        par[t] += v_;
        __syncthreads();
    }
    int run = (t == 0) ? 0 : par[t - 1];
    for (int i = 0; i < 12; ++i) {
        row_start[base + i] = run;
        cursor[base + i]    = run;
        run += counts[base + i];
    }
    if (t == 1023) row_start[Vn] = En;        // sentinel
}

__global__ void fill_k(const int* __restrict__ src, const int* __restrict__ dst,
                       const float* __restrict__ ew, int* __restrict__ cursor,
                       Edge* __restrict__ csr) {
    int e = blockIdx.x * 256 + threadIdx.x;
    int d = dst[e];
    int p = atomicAdd(&cursor[d], 1);
    Edge ed; ed.s = src[e]; ed.w = ew[e];
    csr[p] = ed;
}

// ---------- sparse L apply + Chebyshev combine, XCD-sliced by batch ----------
// r7 form EXACT (best measured; separate launches for cross-XCD coherence --
// the r8 cooperative merge read stale L2; launch boundaries do the flush).
// 8 slices x 512B; slice = blockIdx & 7; per-XCD gather working set 6.3 MB.
// PREV: 0 -> out = L y ; 1 -> out = 2 L y - prev   (bf16 node-major [V][2048])
template<int PREV>
__global__ __launch_bounds__(256)
void lmul_k(const u16* __restrict__ yb, const u16* __restrict__ prevb,
            u16* __restrict__ outb, const int* __restrict__ row_start,
            const Edge* __restrict__ csr)
{
    int slice = blockIdx.x & 7;
    int v     = (blockIdx.x >> 3) * 8 + (threadIdx.x >> 5);
    int t     = threadIdx.x & 31;
    int s0    = row_start[v];
    int cnt   = row_start[v + 1] - s0;
    size_t soff = (size_t)slice * 256 + (size_t)t * 8;
    float acc[8] = {0.f,0.f,0.f,0.f,0.f,0.f,0.f,0.f};
    for (int j0 = 0; j0 < cnt; j0 += 8) {
        int ss[8]; float ww[8];
        #pragma unroll
        for (int u = 0; u < 8; ++u) {
            int j = j0 + u;
            bool ok = j < cnt;
            Edge e = csr[s0 + (ok ? j : 0)];
            ss[u] = e.s; ww[u] = ok ? e.w : 0.f;
        }
        u16x8 g[8];
        #pragma unroll
        for (int u = 0; u < 8; ++u)
            g[u] = *(const u16x8*)(yb + (size_t)ss[u] * 2048 + soff);
        #pragma unroll
        for (int u = 0; u < 8; ++u)
            #pragma unroll
            for (int j8 = 0; j8 < 8; ++j8) acc[j8] += ww[u] * bf2f(g[u][j8]);
    }
    u16x8 r;
    if (PREV) {
        u16x8 pu = *(const u16x8*)(prevb + (size_t)v * 2048 + soff);
        #pragma unroll
        for (int j8 = 0; j8 < 8; ++j8) r[j8] = f2bf(2.0f * acc[j8] - bf2f(pu[j8]));
    } else {
        #pragma unroll
        for (int j8 = 0; j8 < 8; ++j8) r[j8] = f2bf(acc[j8]);
    }
    *(u16x8*)(outb + (size_t)v * 2048 + soff) = r;
}

// ---------- GEMM: out[m][o] = sum_{k,i} T_k[m][i] * W[k][i][o] + bias ----------
// r7 config EXACT (best): BM=128, BN=256, BK=64; 8 waves 2(m)x4(n), 4x4 of
// 16x16x32 MFMA per wave. XOR chunk swizzle (T2). Triple-buffered LDS (3x48KB),
// ONE raw s_barrier per K-tile, counted s_waitcnt vmcnt(6), distance-2 prefetch,
// setprio around MFMA. Epilogue: bf16 C staged through LDS -> contiguous full
// 512B row stores; cb aliases x1 (block M sole reader+writer of its 128 rows).
__device__ __forceinline__ void stage_tile(const u16* __restrict__ Ak, int k0,
                                           const u16* __restrict__ wt, int kt,
                                           int m0, int tid, int wave,
                                           char* bufA, char* bufB)
{
    // A tile: 128 rows x 64k = 16KB = 1024 chunks; 2 per thread
    #pragma unroll
    for (int r = 0; r < 2; ++r) {
        int g  = r * 512 + tid;
        int ml = g >> 3;
        int c  = (g & 7) ^ (ml & 7);
        load_lds16(Ak + ((size_t)(m0 + ml)) * 256 + k0 + c * 8,
                   bufA + r * 8192 + wave * 1024);
    }
    // B tile: 256 o-rows x 64k = 32KB = 2048 chunks; 4 per thread
    #pragma unroll
    for (int r = 0; r < 4; ++r) {
        int g = r * 512 + tid;
        int o = g >> 3;
        int c = (g & 7) ^ (o & 7);
        load_lds16(wt + (size_t)o * 1024 + kt * 64 + c * 8,
                   bufB + r * 8192 + wave * 1024);
    }
}

__global__ __launch_bounds__(512)
void gemm_k(const u16* __restrict__ x0, const u16* __restrict__ x1,
            const u16* __restrict__ x2, const u16* __restrict__ x3,
            const u16* __restrict__ wt, const float* __restrict__ bias,
            u16* cbp, float* __restrict__ sums, float* __restrict__ sumsq)
{
    alignas(16) __shared__ char lds[147456];  // 3 bufs x (A 16KB @ +0, B 32KB @ +16384)
    int tid  = threadIdx.x;
    int wave = tid >> 6;                      // 0..7
    int lane = tid & 63;
    int m0   = blockIdx.x * 128;
    int wm   = wave & 1;                      // m-half (0/1)
    int wn   = wave >> 1;                     // n-quarter (0..3)

    f32x4 acc[4][4];
    #pragma unroll
    for (int a = 0; a < 4; ++a)
        #pragma unroll
        for (int b = 0; b < 4; ++b) acc[a][b] = (f32x4){0.f,0.f,0.f,0.f};

    // prologue: stage tiles 0 and 1 (kt=0: ks=0,k0=0; kt=1: ks=0,k0=64)
    stage_tile(x0, 0,  wt, 0, m0, tid, wave, (char*)lds,         (char*)lds + 16384);
    stage_tile(x0, 64, wt, 1, m0, tid, wave, (char*)lds + 49152, (char*)lds + 49152 + 16384);

    int cb = 0;   // compute buffer (tile t lives in buf t%3)
    int pb = 2;   // prefetch buffer (tile t+2)
    for (int t = 0; t < 16; ++t) {
        // tile t's 6 loads done; tile t+1's 6 remain in flight (last tile: drain)
        if (t < 15) asm volatile("s_waitcnt vmcnt(6) lgkmcnt(0)" ::: "memory");
        else        asm volatile("s_waitcnt vmcnt(0) lgkmcnt(0)" ::: "memory");
        __builtin_amdgcn_s_barrier();
        __builtin_amdgcn_sched_barrier(0);
        if (t < 14) {
            int kt = t + 2;
            int ks = kt >> 2;
            int k0 = (kt & 3) * 64;
            const u16* Ak = (ks == 0) ? x0 : (ks == 1) ? x1 : (ks == 2) ? x2 : x3;
            stage_tile(Ak, k0, wt, kt, m0, tid, wave,
                       (char*)lds + pb * 49152, (char*)lds + pb * 49152 + 16384);
        }
        const char* Ab = (const char*)lds + cb * 49152;
        const char* Bb = Ab + 16384;
        #pragma unroll
        for (int kstep = 0; kstep < 2; ++kstep) {
            int cidx = kstep * 4 + (lane >> 4);
            int row  = lane & 15;
            bf16x8 af[4], bfr[4];
            #pragma unroll
            for (int mt = 0; mt < 4; ++mt) {
                int m16 = wm * 64 + mt * 16 + row;
                af[mt] = *(const bf16x8*)(Ab + (size_t)(m16 * 8 + (cidx ^ (m16 & 7))) * 16);
            }
            #pragma unroll
            for (int nt = 0; nt < 4; ++nt) {
                int ol = wn * 64 + nt * 16 + row;
                bfr[nt] = *(const bf16x8*)(Bb + (size_t)(ol * 8 + (cidx ^ (ol & 7))) * 16);
            }
            __builtin_amdgcn_s_setprio(1);
            #pragma unroll
            for (int mt = 0; mt < 4; ++mt)
                #pragma unroll
                for (int nt = 0; nt < 4; ++nt)
                    acc[mt][nt] = __builtin_amdgcn_mfma_f32_16x16x32_bf16(
                        af[mt], bfr[nt], acc[mt][nt], 0, 0, 0);
            __builtin_amdgcn_s_setprio(0);
        }
        cb = (cb == 2) ? 0 : cb + 1;
        pb = (pb == 2) ? 0 : pb + 1;
    }

    // ---- epilogue ----
    // Phase 1: quantize to bf16, write into LDS tile [128][256] bf16 (64KB @ lds+0)
    // with 16B-chunk XOR swizzle (chunk c of row m at slot c^(m&7)).
    // BN stats from the QUANTIZED values (self-consistent normalization).
    __syncthreads();   // all waves done reading tile-15 fragments
    int crow = lane & 15, quad = lane >> 4;
    #pragma unroll
    for (int nt = 0; nt < 4; ++nt) {
        int o = wn * 64 + nt * 16 + crow;
        int c_o = o >> 3, o_in = (o & 7) * 2;
        float bv = bias[o];
        float ps = 0.f, pq = 0.f;
        #pragma unroll
        for (int mt = 0; mt < 4; ++mt) {
            #pragma unroll
            for (int r = 0; r < 4; ++r) {
                int ml = wm * 64 + mt * 16 + quad * 4 + r;
                u16 q = f2bf(acc[mt][nt][r] + bv);
                float vq = bf2f(q);
                *(u16*)(lds + (size_t)ml * 512 + (size_t)(c_o ^ (ml & 7)) * 16 + o_in) = q;
                ps += vq; pq += vq * vq;
            }
        }
        ps += __shfl_down(ps, 32, 64);  pq += __shfl_down(pq, 32, 64);
        ps += __shfl_down(ps, 16, 64);  pq += __shfl_down(pq, 16, 64);
        if (quad == 0) { atomicAdd(&sums[o], ps); atomicAdd(&sumsq[o], pq); }
    }
    __syncthreads();
    // Phase 2: stream out contiguous full rows. 4096 chunks of 16B; 8/thread.
    #pragma unroll
    for (int rr = 0; rr < 8; ++rr) {
        int ch = rr * 512 + tid;
        int ml = ch >> 5, c = ch & 31;
        u16x8 vv = *(const u16x8*)(lds + (size_t)ml * 512 + (size_t)(c ^ (ml & 7)) * 16);
        *(u16x8*)(cbp + (size_t)(m0 + ml) * 256 + c * 8) = vv;
    }
}

// cb [m][256] bf16 -> out [b][v][256] f32 (m = v*8+b), finalize+BN+ReLU fused.
// Each block redundantly computes scale/shift from sums/sumsq (hot L2) -- no
// separate finalize dispatch. cb dead after: NT loads. Output NT stores.
__global__ void bn_relu_k(const u16* __restrict__ cb, float* __restrict__ outp,
                          const float* __restrict__ sums, const float* __restrict__ sumsq,
                          const float* __restrict__ gamma, const float* __restrict__ beta) {
    __shared__ float ssc[256], ssh[256];
    int t = threadIdx.x;
    {
        const float invM = 1.0f / (float)Mrows;
        float mean = sums[t] * invM;
        float var  = sumsq[t] * invM - mean * mean;
        float sc   = gamma[t] * rsqrtf(var + 1e-5f);
        ssc[t] = sc;
        ssh[t] = beta[t] - mean * sc;
    }
    __syncthreads();
    size_t p = ((size_t)blockIdx.x * 256 + t) * 8;   // covers 25165824 elems
    int o0 = (int)(p & 255);
    int m  = (int)(p >> 8);
    u16x8 v = __builtin_nontemporal_load((const u16x8*)(cb + p));
    float* dst = outp + ((size_t)((m & 7) * Vn + (m >> 3))) * 256 + o0;
    f32x4 a, c;
    #pragma unroll
    for (int i = 0; i < 4; ++i) {
        a[i] = fmaxf(bf2f(v[i])     * ssc[o0 + i]     + ssh[o0 + i],     0.f);
        c[i] = fmaxf(bf2f(v[4 + i]) * ssc[o0 + 4 + i] + ssh[o0 + 4 + i], 0.f);
    }
    __builtin_nontemporal_store(a, (f32x4*)dst);
    __builtin_nontemporal_store(c, (f32x4*)(dst + 4));
}

extern "C" void kernel_launch(void* const* d_in, const int* in_sizes, int n_in,
                              void* d_out, int out_size, void* d_ws, size_t ws_size,
                              hipStream_t stream) {
    const float* x     = (const float*)d_in[0];
    const float* ew    = (const float*)d_in[1];
    const float* w     = (const float*)d_in[2];
    const float* bias  = (const float*)d_in[3];
    const float* gamma = (const float*)d_in[4];
    const float* beta  = (const float*)d_in[5];
    const int*   esrc  = (const int*)d_in[6];
    const int*   edst  = (const int*)d_in[7];
    float* outp = (float*)d_out;
    char*  ws   = (char*)d_ws;

    u16*   xb        = (u16*)  (ws + 0);           // 50331648 B each, bf16 [V][2048]
    u16*   x1        = (u16*)  (ws + 50331648);
    u16*   x2        = (u16*)  (ws + 100663296);
    u16*   x3        = (u16*)  (ws + 150994944);
    u16*   wt        = (u16*)  (ws + 201326592);   // 524288 B
    Edge*  csr       = (Edge*) (ws + 201850880);   // 786432 B
    int*   counts    = (int*)  (ws + 202637312);   // 49152 B
    int*   row_start = (int*)  (ws + 202686464);   // 49412 B (V+1)
    int*   cursor    = (int*)  (ws + 202736128);   // 49152 B
    float* sums      = (float*)(ws + 202785280);   // 1024 B (+1024 sumsq)
    float* sumsq     = (float*)(ws + 202786304);

    hipMemsetAsync(counts, 0, 49152, stream);

    // merged: cvt (12288) | wtrans (8) | count (384) | zero-stats (1)
    prep_k<<<Vn + 8 + 384 + 1, 256, 0, stream>>>(x, xb, w, wt, edst, counts, sums);

    scan_k<<<1, 1024, 0, stream>>>(counts, row_start, cursor);
    fill_k<<<384, 256, 0, stream>>>(esrc, edst, ew, cursor, csr);

    // T1 = L x ; T2 = 2 L T1 - x ; T3 = 2 L T2 - T1   (all bf16 node-major)
    lmul_k<0><<<Vn, 256, 0, stream>>>(xb, nullptr, x1, row_start, csr);
    lmul_k<1><<<Vn, 256, 0, stream>>>(x1, xb,      x2, row_start, csr);
    lmul_k<1><<<Vn, 256, 0, stream>>>(x2, x1,      x3, row_start, csr);

    // C (bf16, [m][256]) aliases x1 -- per-block exclusive rows; clean full-row
    // stores via LDS-transposed epilogue.
    gemm_k<<<Mrows / 128, 512, 0, stream>>>(xb, x1, x2, x3, wt, bias,
                                            (u16*)x1, sums, sumsq);

    bn_relu_k<<<12288, 256, 0, stream>>>((const u16*)x1, outp, sums, sumsq, gamma, beta);
}